// Round 4
// baseline (357.722 us; speedup 1.0000x reference)
//
#include <hip/hip_runtime.h>

#define BB 4
#define H 320
#define W 768
#define P (H*W)           // 245760
#define NPIX (BB*P)       // 983040

#define TX 32
#define TY 8
#define TW (TX+6)  // 38
#define TH (TY+6)  // 14
#define HALO (TW*TH)      // 532
#define NBX (W/TX)        // 24
#define NBY (H/TY)        // 40
#define NBLK (NBX*NBY*BB) // 3840

typedef float f4 __attribute__((ext_vector_type(4)));

// gray formula identical to the (verified) separate gray kernel
__device__ __forceinline__ float gray_at(const float* __restrict__ img3, int o) {
    return (0.299f * img3[o] + 0.587f * img3[P + o] + 0.114f * img3[2 * P + o]) * 255.f;
}

// Bilinear sample of gray(img3) at (fx,fy): gray is linear, so computing gray
// at the 4 RGB corners then lerping == lerping a precomputed gray plane.
__device__ __forceinline__ float bilinear_gray(const float* __restrict__ img3, float fx, float fy) {
    float x0 = floorf(fx), y0 = floorf(fy);
    float wx = fx - x0, wy = fy - y0;
    float x0c = fminf(fmaxf(x0,       0.f), (float)(W - 1));
    float x1c = fminf(fmaxf(x0 + 1.f, 0.f), (float)(W - 1));
    float y0c = fminf(fmaxf(y0,       0.f), (float)(H - 1));
    float y1c = fminf(fmaxf(y0 + 1.f, 0.f), (float)(H - 1));
    int x0i = (int)x0c, x1i = (int)x1c, y0i = (int)y0c, y1i = (int)y1c;
    float Ia = gray_at(img3, y0i * W + x0i), Ib = gray_at(img3, y0i * W + x1i);
    float Ic = gray_at(img3, y1i * W + x0i), Id = gray_at(img3, y1i * W + x1i);
    float omx = 1.f - wx, omy = 1.f - wy;
    return Ia * omx * omy + Ib * wx * omy + Ic * omx * wy + Id * wx * wy;
}

// Single fused kernel: gray + warp + census + distance + charbonnier + reduce.
// Trans budget per tap: 2x rsq (product trick per loss) + 1x rcp (shared
// across the two losses) = 3, down from 6. Identity used:
//   (t1-t2)^2 = (a^2*qb + b^2*qa)*s^2 - 2ab*s,  s = rsq(qa*qb),
//   a^2*qb + b^2*qa = 2*qa*qb - 0.81*(qa+qb)
// Final reduce folded in via last-block-done counter (agent-scope atomics);
// summation order identical to the old reduce_kernel.
__global__ __launch_bounds__(256, 5)
void fused_kernel(const float* __restrict__ former, const float* __restrict__ latter,
                  const float* __restrict__ flow1, const float* __restrict__ flow2,
                  const float* __restrict__ fw_mask, const float* __restrict__ bw_mask,
                  float* __restrict__ partials, unsigned* __restrict__ counter,
                  float* __restrict__ out) {
    __shared__ f4 sT[HALO];
    const int b   = blockIdx.z;
    const int tx0 = blockIdx.x * TX;
    const int ty0 = blockIdx.y * TY;
    const int tid = threadIdx.x;

    const float* pF3 = former + (size_t)b * 3 * P;
    const float* pL3 = latter + (size_t)b * 3 * P;
    const float* pU1 = flow1 + (size_t)b * 2 * P;
    const float* pU2 = flow2 + (size_t)b * 2 * P;

    // Stage 1: gray + warped-gray tiles into interleaved LDS {A,B,C,D}.
    for (int i = tid; i < HALO; i += 256) {
        int ly = i / TW, lx = i - ly * TW;
        int gx = min(max(tx0 - 3 + lx, 0), W - 1);
        int gy = min(max(ty0 - 3 + ly, 0), H - 1);
        int o = gy * W + gx;
        float A = gray_at(pF3, o);
        float C = gray_at(pL3, o);
        float u1 = pU1[o], v1 = pU1[P + o];
        float u2 = pU2[o], v2 = pU2[P + o];
        float Bv = bilinear_gray(pL3, (float)gx + u1, (float)gy + v1);
        float D  = bilinear_gray(pF3, (float)gx + u2, (float)gy + v2);
        sT[i] = (f4){A, Bv, C, D};
    }
    __syncthreads();

    const int lx = tid & 31, ly = tid >> 5;
    const int x = tx0 + lx, y = ty0 + ly;
    float sum1 = 0.f, sum2 = 0.f;

    if (x >= 3 && x < W - 3 && y >= 3 && y < H - 3) {
        const float m1 = fw_mask[(size_t)b * P + y * W + x];
        const float m2 = bw_mask[(size_t)b * P + y * W + x];
        const int c = (ly + 3) * TW + (lx + 3);
        const f4 cv = sT[c];
        const float c1 = cv.x, c2 = cv.y, c3 = cv.z, c4 = cv.w;
        float acc1a = 0.f, acc1b = 0.f, acc2a = 0.f, acc2b = 0.f;
#pragma unroll
        for (int dy = 0; dy < 7; ++dy) {
            const int ro = (ly + dy) * TW + lx;
#pragma unroll
            for (int dx = 0; dx < 7; ++dx) {
                if (dy == 3 && dx == 3) continue;    // center tap == 0 exactly
                const f4 n = sT[ro + dx];            // one ds_read_b128
                // ---- loss 1: d1 = (t1 - t2)^2 with ONE rsq ----
                const float a1 = n.x - c1, b1 = n.y - c2;
                const float qa1 = fmaf(a1, a1, 0.81f), qb1 = fmaf(b1, b1, 0.81f);
                const float pr1 = qa1 * qb1;
                const float s1 = __builtin_amdgcn_rsqf(pr1);
                const float num1 = fmaf(-0.81f, qa1 + qb1, pr1 + pr1);
                const float d1 = fmaf(num1, s1 * s1, ((a1 * b1) * s1) * -2.f);
                // ---- loss 2 ----
                const float a2 = n.z - c3, b2 = n.w - c4;
                const float qa2 = fmaf(a2, a2, 0.81f), qb2 = fmaf(b2, b2, 0.81f);
                const float pr2 = qa2 * qb2;
                const float s2 = __builtin_amdgcn_rsqf(pr2);
                const float num2 = fmaf(-0.81f, qa2 + qb2, pr2 + pr2);
                const float d2 = fmaf(num2, s2 * s2, ((a2 * b2) * s2) * -2.f);
                // ---- shared rcp: d1/e1 = d1*e2*rcp(e1*e2), d2/e2 = d2*e1*rcp(e1*e2)
                const float e1 = d1 + 0.1f, e2 = d2 + 0.1f;
                const float ir = __builtin_amdgcn_rcpf(e1 * e2);
                const float g1 = (d1 * e2) * ir;
                const float g2 = (d2 * e1) * ir;
                if (dx & 1) { acc1a += g1; acc2a += g2; }
                else        { acc1b += g1; acc2b += g2; }
            }
        }
        const float dist1 = acc1a + acc1b;
        const float dist2 = acc2a + acc2b;
        sum1 = exp2f(0.45f * log2f(fmaf(dist1, dist1, 1e-6f))) * m1;
        sum2 = exp2f(0.45f * log2f(fmaf(dist2, dist2, 1e-6f))) * m2;
    }

#pragma unroll
    for (int off = 32; off; off >>= 1) {
        sum1 += __shfl_down(sum1, off, 64);
        sum2 += __shfl_down(sum2, off, 64);
    }
    __shared__ float red[8];
    const int wave = tid >> 6, lane = tid & 63;
    if (lane == 0) { red[wave] = sum1; red[4 + wave] = sum2; }
    __syncthreads();
    if (tid == 0) {
        const int blk = (blockIdx.z * NBY + blockIdx.y) * NBX + blockIdx.x;
        partials[2 * blk]     = red[0] + red[1] + red[2] + red[3];
        partials[2 * blk + 1] = red[4] + red[5] + red[6] + red[7];
    }

    // ---- last-block final reduce (replaces reduce_kernel, same sum order) ----
    __shared__ unsigned sLast;
    if (tid == 0) {
        __threadfence();  // release this block's partials to device scope
        unsigned prev = __hip_atomic_fetch_add(counter, 1u, __ATOMIC_ACQ_REL,
                                               __HIP_MEMORY_SCOPE_AGENT);
        sLast = (prev == NBLK - 1) ? 1u : 0u;
    }
    __syncthreads();
    if (sLast) {
        float s1 = 0.f, s2 = 0.f;
        for (int i = tid; i < NBLK; i += 256) {
            s1 += __hip_atomic_load(&partials[2 * i],     __ATOMIC_RELAXED, __HIP_MEMORY_SCOPE_AGENT);
            s2 += __hip_atomic_load(&partials[2 * i + 1], __ATOMIC_RELAXED, __HIP_MEMORY_SCOPE_AGENT);
        }
#pragma unroll
        for (int off = 32; off; off >>= 1) {
            s1 += __shfl_down(s1, off, 64);
            s2 += __shfl_down(s2, off, 64);
        }
        __shared__ float red2[8];
        if (lane == 0) { red2[wave] = s1; red2[4 + wave] = s2; }
        __syncthreads();
        if (tid == 0) {
            out[0] = (red2[0] + red2[1] + red2[2] + red2[3]) * (1.0f / NPIX);
            out[1] = (red2[4] + red2[5] + red2[6] + red2[7]) * (1.0f / NPIX);
        }
    }
}

extern "C" void kernel_launch(void* const* d_in, const int* in_sizes, int n_in,
                              void* d_out, int out_size, void* d_ws, size_t ws_size,
                              hipStream_t stream) {
    (void)in_sizes; (void)n_in; (void)out_size; (void)ws_size;
    const float* former  = (const float*)d_in[0];
    const float* latter  = (const float*)d_in[1];
    const float* flow1   = (const float*)d_in[2];
    const float* flow2   = (const float*)d_in[3];
    const float* fw_mask = (const float*)d_in[4];
    const float* bw_mask = (const float*)d_in[5];
    float* out = (float*)d_out;
    float* ws  = (float*)d_ws;
    float* partials   = ws;                              // 2*NBLK floats
    unsigned* counter = (unsigned*)(ws + 2 * NBLK);      // 1 uint

    hipMemsetAsync(counter, 0, sizeof(unsigned), stream);
    fused_kernel<<<dim3(NBX, NBY, BB), 256, 0, stream>>>(former, latter, flow1, flow2,
                                                         fw_mask, bw_mask,
                                                         partials, counter, out);
}

// Round 6
// 295.614 us; speedup vs baseline: 1.2101x; 1.2101x over previous
//
#include <hip/hip_runtime.h>

#define BB 4
#define H 320
#define W 768
#define P (H*W)           // 245760
#define NPIX (BB*P)       // 983040
#define P4 (P/4)          // 61440
#define NP4 (NPIX/4)      // 245760

#define TX 32
#define TY 8
#define TW (TX+6)  // 38
#define TH (TY+6)  // 14
#define HALO (TW*TH)      // 532
#define NBX (W/TX)        // 24
#define NBY (H/TY)        // 40
#define NBLK (NBX*NBY*BB) // 3840

typedef float f4 __attribute__((ext_vector_type(4)));

// ---------------- gray kernel (float4-vectorized) ----------------
// Also resets the last-block counter so no separate memset dispatch is needed
// (stream order guarantees it lands before fused_kernel reads it).
__global__ __launch_bounds__(256)
void gray_kernel(const float* __restrict__ former,
                 const float* __restrict__ latter,
                 float* __restrict__ gf, float* __restrict__ gl,
                 unsigned* __restrict__ counter) {
    int idx = blockIdx.x * blockDim.x + threadIdx.x;
    if (idx == 0) *counter = 0u;
    if (idx >= NP4) return;
    int b = idx / P4;
    int r4 = idx - b * P4;
    const float* fb = former + (size_t)b * 3 * P;
    const float* lb = latter + (size_t)b * 3 * P;
    const f4 fr = *((const f4*)fb + r4);
    const f4 fg = *((const f4*)(fb + P) + r4);
    const f4 fbl = *((const f4*)(fb + 2 * P) + r4);
    const f4 lr = *((const f4*)lb + r4);
    const f4 lg = *((const f4*)(lb + P) + r4);
    const f4 lbl = *((const f4*)(lb + 2 * P) + r4);
    f4 go, lo;
#pragma unroll
    for (int k = 0; k < 4; ++k) {
        go[k] = (0.299f * fr[k] + 0.587f * fg[k] + 0.114f * fbl[k]) * 255.f;
        lo[k] = (0.299f * lr[k] + 0.587f * lg[k] + 0.114f * lbl[k]) * 255.f;
    }
    *((f4*)gf + (size_t)b * P4 + r4) = go;
    *((f4*)gl + (size_t)b * P4 + r4) = lo;
}

__device__ __forceinline__ float bilinear(const float* __restrict__ img, float fx, float fy) {
    float x0 = floorf(fx), y0 = floorf(fy);
    float wx = fx - x0, wy = fy - y0;
    float x0c = fminf(fmaxf(x0,       0.f), (float)(W - 1));
    float x1c = fminf(fmaxf(x0 + 1.f, 0.f), (float)(W - 1));
    float y0c = fminf(fmaxf(y0,       0.f), (float)(H - 1));
    float y1c = fminf(fmaxf(y0 + 1.f, 0.f), (float)(H - 1));
    int x0i = (int)x0c, x1i = (int)x1c, y0i = (int)y0c, y1i = (int)y1c;
    float Ia = img[y0i * W + x0i], Ib = img[y0i * W + x1i];
    float Ic = img[y1i * W + x0i], Id = img[y1i * W + x1i];
    float omx = 1.f - wx, omy = 1.f - wy;
    return Ia * omx * omy + Ib * wx * omy + Ic * omx * wy + Id * wx * wy;
}

// ---------------- fused warp + census + distance + charbonnier + reduce ------
// Round-3 tile structure (interleaved f4 LDS, one ds_read_b128/tap) +
// round-4 HW-validated 3-transcendental tap:
//   (t1-t2)^2 = (2*qa*qb - 0.81*(qa+qb))*s^2 - 2ab*s,  s = rsq(qa*qb)
//   shared rcp: d1/e1 = d1*e2*rcp(e1*e2), d2/e2 = d2*e1*rcp(e1*e2)
// + round-4 HW-validated last-block final reduce (agent-scope atomics).
__global__ __launch_bounds__(256, 5)
void fused_kernel(const float* __restrict__ gf, const float* __restrict__ gl,
                  const float* __restrict__ flow1, const float* __restrict__ flow2,
                  const float* __restrict__ fw_mask, const float* __restrict__ bw_mask,
                  float* __restrict__ partials, unsigned* __restrict__ counter,
                  float* __restrict__ out) {
    __shared__ f4 sT[HALO];
    const int b   = blockIdx.z;
    const int tx0 = blockIdx.x * TX;
    const int ty0 = blockIdx.y * TY;
    const int tid = threadIdx.x;

    const float* pGF = gf + (size_t)b * P;
    const float* pGL = gl + (size_t)b * P;
    const float* pU1 = flow1 + (size_t)b * 2 * P;
    const float* pU2 = flow2 + (size_t)b * 2 * P;

    for (int i = tid; i < HALO; i += 256) {
        int ly = i / TW, lx = i - ly * TW;
        int gx = min(max(tx0 - 3 + lx, 0), W - 1);
        int gy = min(max(ty0 - 3 + ly, 0), H - 1);
        int o = gy * W + gx;
        float A = pGF[o];
        float C = pGL[o];
        float u1 = pU1[o], v1 = pU1[P + o];
        float u2 = pU2[o], v2 = pU2[P + o];
        float Bv = bilinear(pGL, (float)gx + u1, (float)gy + v1);
        float D  = bilinear(pGF, (float)gx + u2, (float)gy + v2);
        sT[i] = (f4){A, Bv, C, D};
    }
    __syncthreads();

    const int lx = tid & 31, ly = tid >> 5;
    const int x = tx0 + lx, y = ty0 + ly;
    float sum1 = 0.f, sum2 = 0.f;

    if (x >= 3 && x < W - 3 && y >= 3 && y < H - 3) {
        const float m1 = fw_mask[(size_t)b * P + y * W + x];
        const float m2 = bw_mask[(size_t)b * P + y * W + x];
        const int c = (ly + 3) * TW + (lx + 3);
        const f4 cv = sT[c];
        const float c1 = cv.x, c2 = cv.y, c3 = cv.z, c4 = cv.w;
        float acc1a = 0.f, acc1b = 0.f, acc2a = 0.f, acc2b = 0.f;
#pragma unroll
        for (int dy = 0; dy < 7; ++dy) {
            const int ro = (ly + dy) * TW + lx;
#pragma unroll
            for (int dx = 0; dx < 7; ++dx) {
                if (dy == 3 && dx == 3) continue;    // center tap == 0 exactly
                const f4 n = sT[ro + dx];            // one ds_read_b128
                // loss 1: (t1-t2)^2 via ONE rsq
                const float a1 = n.x - c1, b1 = n.y - c2;
                const float qa1 = fmaf(a1, a1, 0.81f), qb1 = fmaf(b1, b1, 0.81f);
                const float pr1 = qa1 * qb1;
                const float s1 = __builtin_amdgcn_rsqf(pr1);
                const float num1 = fmaf(-0.81f, qa1 + qb1, pr1 + pr1);
                const float d1 = fmaf(num1, s1 * s1, ((a1 * b1) * s1) * -2.f);
                // loss 2
                const float a2 = n.z - c3, b2 = n.w - c4;
                const float qa2 = fmaf(a2, a2, 0.81f), qb2 = fmaf(b2, b2, 0.81f);
                const float pr2 = qa2 * qb2;
                const float s2 = __builtin_amdgcn_rsqf(pr2);
                const float num2 = fmaf(-0.81f, qa2 + qb2, pr2 + pr2);
                const float d2 = fmaf(num2, s2 * s2, ((a2 * b2) * s2) * -2.f);
                // shared rcp across the two losses
                const float e1 = d1 + 0.1f, e2 = d2 + 0.1f;
                const float ir = __builtin_amdgcn_rcpf(e1 * e2);
                const float g1 = (d1 * e2) * ir;
                const float g2 = (d2 * e1) * ir;
                if (dx & 1) { acc1a += g1; acc2a += g2; }
                else        { acc1b += g1; acc2b += g2; }
            }
        }
        const float dist1 = acc1a + acc1b;
        const float dist2 = acc2a + acc2b;
        sum1 = exp2f(0.45f * log2f(fmaf(dist1, dist1, 1e-6f))) * m1;
        sum2 = exp2f(0.45f * log2f(fmaf(dist2, dist2, 1e-6f))) * m2;
    }

#pragma unroll
    for (int off = 32; off; off >>= 1) {
        sum1 += __shfl_down(sum1, off, 64);
        sum2 += __shfl_down(sum2, off, 64);
    }
    __shared__ float red[8];
    const int wave = tid >> 6, lane = tid & 63;
    if (lane == 0) { red[wave] = sum1; red[4 + wave] = sum2; }
    __syncthreads();
    if (tid == 0) {
        const int blk = (blockIdx.z * NBY + blockIdx.y) * NBX + blockIdx.x;
        partials[2 * blk]     = red[0] + red[1] + red[2] + red[3];
        partials[2 * blk + 1] = red[4] + red[5] + red[6] + red[7];
    }

    // ---- last-block final reduce (HW-validated in round 4) ----
    __shared__ unsigned sLast;
    if (tid == 0) {
        __threadfence();  // release this block's partials to device scope
        unsigned prev = __hip_atomic_fetch_add(counter, 1u, __ATOMIC_ACQ_REL,
                                               __HIP_MEMORY_SCOPE_AGENT);
        sLast = (prev == NBLK - 1) ? 1u : 0u;
    }
    __syncthreads();
    if (sLast) {
        float s1 = 0.f, s2 = 0.f;
        for (int i = tid; i < NBLK; i += 256) {
            s1 += __hip_atomic_load(&partials[2 * i],     __ATOMIC_RELAXED, __HIP_MEMORY_SCOPE_AGENT);
            s2 += __hip_atomic_load(&partials[2 * i + 1], __ATOMIC_RELAXED, __HIP_MEMORY_SCOPE_AGENT);
        }
#pragma unroll
        for (int off = 32; off; off >>= 1) {
            s1 += __shfl_down(s1, off, 64);
            s2 += __shfl_down(s2, off, 64);
        }
        __shared__ float red2[8];
        if (lane == 0) { red2[wave] = s1; red2[4 + wave] = s2; }
        __syncthreads();
        if (tid == 0) {
            out[0] = (red2[0] + red2[1] + red2[2] + red2[3]) * (1.0f / NPIX);
            out[1] = (red2[4] + red2[5] + red2[6] + red2[7]) * (1.0f / NPIX);
        }
    }
}

extern "C" void kernel_launch(void* const* d_in, const int* in_sizes, int n_in,
                              void* d_out, int out_size, void* d_ws, size_t ws_size,
                              hipStream_t stream) {
    (void)in_sizes; (void)n_in; (void)out_size; (void)ws_size;
    const float* former  = (const float*)d_in[0];
    const float* latter  = (const float*)d_in[1];
    const float* flow1   = (const float*)d_in[2];
    const float* flow2   = (const float*)d_in[3];
    const float* fw_mask = (const float*)d_in[4];
    const float* bw_mask = (const float*)d_in[5];
    float* out = (float*)d_out;
    float* ws  = (float*)d_ws;
    float* gf       = ws;                         // NPIX floats
    float* gl       = ws + NPIX;                  // NPIX floats
    float* partials = ws + 2 * (size_t)NPIX;      // 2*NBLK floats
    unsigned* counter = (unsigned*)(ws + 2 * (size_t)NPIX + 2 * NBLK);

    gray_kernel<<<(NP4 + 255) / 256, 256, 0, stream>>>(former, latter, gf, gl, counter);
    fused_kernel<<<dim3(NBX, NBY, BB), 256, 0, stream>>>(gf, gl, flow1, flow2,
                                                         fw_mask, bw_mask,
                                                         partials, counter, out);
}

// Round 7
// 196.485 us; speedup vs baseline: 1.8206x; 1.5045x over previous
//
#include <hip/hip_runtime.h>

#define BB 4
#define H 320
#define W 768
#define P (H*W)           // 245760
#define NPIX (BB*P)       // 983040
#define P4 (P/4)          // 61440
#define NP4 (NPIX/4)      // 245760

#define TX 32
#define TY 8
#define TW (TX+6)  // 38
#define TH (TY+6)  // 14
#define HALO (TW*TH)      // 532
#define NBX (W/TX)        // 24
#define NBY (H/TY)        // 40
#define NBLK (NBX*NBY*BB) // 3840

typedef float f4 __attribute__((ext_vector_type(4)));

// ---------------- gray kernel (float4-vectorized) ----------------
// Also resets the last-block counter (stream order puts it before fused).
__global__ __launch_bounds__(256)
void gray_kernel(const float* __restrict__ former,
                 const float* __restrict__ latter,
                 float* __restrict__ gf, float* __restrict__ gl,
                 unsigned* __restrict__ counter) {
    int idx = blockIdx.x * blockDim.x + threadIdx.x;
    if (idx == 0) *counter = 0u;
    if (idx >= NP4) return;
    int b = idx / P4;
    int r4 = idx - b * P4;
    const float* fb = former + (size_t)b * 3 * P;
    const float* lb = latter + (size_t)b * 3 * P;
    const f4 fr = *((const f4*)fb + r4);
    const f4 fg = *((const f4*)(fb + P) + r4);
    const f4 fbl = *((const f4*)(fb + 2 * P) + r4);
    const f4 lr = *((const f4*)lb + r4);
    const f4 lg = *((const f4*)(lb + P) + r4);
    const f4 lbl = *((const f4*)(lb + 2 * P) + r4);
    f4 go, lo;
#pragma unroll
    for (int k = 0; k < 4; ++k) {
        go[k] = (0.299f * fr[k] + 0.587f * fg[k] + 0.114f * fbl[k]) * 255.f;
        lo[k] = (0.299f * lr[k] + 0.587f * lg[k] + 0.114f * lbl[k]) * 255.f;
    }
    *((f4*)gf + (size_t)b * P4 + r4) = go;
    *((f4*)gl + (size_t)b * P4 + r4) = lo;
}

__device__ __forceinline__ float bilinear(const float* __restrict__ img, float fx, float fy) {
    float x0 = floorf(fx), y0 = floorf(fy);
    float wx = fx - x0, wy = fy - y0;
    float x0c = fminf(fmaxf(x0,       0.f), (float)(W - 1));
    float x1c = fminf(fmaxf(x0 + 1.f, 0.f), (float)(W - 1));
    float y0c = fminf(fmaxf(y0,       0.f), (float)(H - 1));
    float y1c = fminf(fmaxf(y0 + 1.f, 0.f), (float)(H - 1));
    int x0i = (int)x0c, x1i = (int)x1c, y0i = (int)y0c, y1i = (int)y1c;
    float Ia = img[y0i * W + x0i], Ib = img[y0i * W + x1i];
    float Ic = img[y1i * W + x0i], Id = img[y1i * W + x1i];
    float omx = 1.f - wx, omy = 1.f - wy;
    return Ia * omx * omy + Ib * wx * omy + Ic * omx * wy + Id * wx * wy;
}

// ---------------- fused warp + census + distance + charbonnier + reduce ------
// Tail discipline (the R4/R6 poison, now fixed): per-block counter bump is
// RELEASE-only (buffer_wbl2 of a few dirty lines, NO buffer_inv). The old
// __threadfence() + ACQ_REL emitted an L2-wide buffer_inv per block (3840
// invalidations!) destroying L2 tile locality for all co-resident blocks.
// Last block reads partials via relaxed agent-scope atomic loads (cache-
// bypassing), so it needs no acquire-invalidate either.
__global__ __launch_bounds__(256, 5)
void fused_kernel(const float* __restrict__ gf, const float* __restrict__ gl,
                  const float* __restrict__ flow1, const float* __restrict__ flow2,
                  const float* __restrict__ fw_mask, const float* __restrict__ bw_mask,
                  float* __restrict__ partials, unsigned* __restrict__ counter,
                  float* __restrict__ out) {
    __shared__ f4 sT[HALO];
    const int b   = blockIdx.z;
    const int tx0 = blockIdx.x * TX;
    const int ty0 = blockIdx.y * TY;
    const int tid = threadIdx.x;

    const float* pGF = gf + (size_t)b * P;
    const float* pGL = gl + (size_t)b * P;
    const float* pU1 = flow1 + (size_t)b * 2 * P;
    const float* pU2 = flow2 + (size_t)b * 2 * P;

    for (int i = tid; i < HALO; i += 256) {
        int ly = i / TW, lx = i - ly * TW;
        int gx = min(max(tx0 - 3 + lx, 0), W - 1);
        int gy = min(max(ty0 - 3 + ly, 0), H - 1);
        int o = gy * W + gx;
        float A = pGF[o];
        float C = pGL[o];
        float u1 = pU1[o], v1 = pU1[P + o];
        float u2 = pU2[o], v2 = pU2[P + o];
        float Bv = bilinear(pGL, (float)gx + u1, (float)gy + v1);
        float D  = bilinear(pGF, (float)gx + u2, (float)gy + v2);
        sT[i] = (f4){A, Bv, C, D};
    }
    __syncthreads();

    const int lx = tid & 31, ly = tid >> 5;
    const int x = tx0 + lx, y = ty0 + ly;
    float sum1 = 0.f, sum2 = 0.f;

    if (x >= 3 && x < W - 3 && y >= 3 && y < H - 3) {
        const float m1 = fw_mask[(size_t)b * P + y * W + x];
        const float m2 = bw_mask[(size_t)b * P + y * W + x];
        const int c = (ly + 3) * TW + (lx + 3);
        const f4 cv = sT[c];
        const float c1 = cv.x, c2 = cv.y, c3 = cv.z, c4 = cv.w;
        float acc1a = 0.f, acc1b = 0.f, acc2a = 0.f, acc2b = 0.f;
#pragma unroll
        for (int dy = 0; dy < 7; ++dy) {
            const int ro = (ly + dy) * TW + lx;
#pragma unroll
            for (int dx = 0; dx < 7; ++dx) {
                if (dy == 3 && dx == 3) continue;    // center tap == 0 exactly
                const f4 n = sT[ro + dx];            // one ds_read_b128
                // loss 1: (t1-t2)^2 via ONE rsq:  s = rsq(qa*qb)
                const float a1 = n.x - c1, b1 = n.y - c2;
                const float qa1 = fmaf(a1, a1, 0.81f), qb1 = fmaf(b1, b1, 0.81f);
                const float pr1 = qa1 * qb1;
                const float s1 = __builtin_amdgcn_rsqf(pr1);
                const float num1 = fmaf(-0.81f, qa1 + qb1, pr1 + pr1);
                const float d1 = fmaf(num1, s1 * s1, ((a1 * b1) * s1) * -2.f);
                // loss 2
                const float a2 = n.z - c3, b2 = n.w - c4;
                const float qa2 = fmaf(a2, a2, 0.81f), qb2 = fmaf(b2, b2, 0.81f);
                const float pr2 = qa2 * qb2;
                const float s2 = __builtin_amdgcn_rsqf(pr2);
                const float num2 = fmaf(-0.81f, qa2 + qb2, pr2 + pr2);
                const float d2 = fmaf(num2, s2 * s2, ((a2 * b2) * s2) * -2.f);
                // shared rcp across the two losses
                const float e1 = d1 + 0.1f, e2 = d2 + 0.1f;
                const float ir = __builtin_amdgcn_rcpf(e1 * e2);
                const float g1 = (d1 * e2) * ir;
                const float g2 = (d2 * e1) * ir;
                if (dx & 1) { acc1a += g1; acc2a += g2; }
                else        { acc1b += g1; acc2b += g2; }
            }
        }
        const float dist1 = acc1a + acc1b;
        const float dist2 = acc2a + acc2b;
        sum1 = exp2f(0.45f * log2f(fmaf(dist1, dist1, 1e-6f))) * m1;
        sum2 = exp2f(0.45f * log2f(fmaf(dist2, dist2, 1e-6f))) * m2;
    }

#pragma unroll
    for (int off = 32; off; off >>= 1) {
        sum1 += __shfl_down(sum1, off, 64);
        sum2 += __shfl_down(sum2, off, 64);
    }
    __shared__ float red[8];
    const int wave = tid >> 6, lane = tid & 63;
    if (lane == 0) { red[wave] = sum1; red[4 + wave] = sum2; }
    __syncthreads();
    if (tid == 0) {
        const int blk = (blockIdx.z * NBY + blockIdx.y) * NBX + blockIdx.x;
        partials[2 * blk]     = red[0] + red[1] + red[2] + red[3];
        partials[2 * blk + 1] = red[4] + red[5] + red[6] + red[7];
    }

    // ---- last-block final reduce: RELEASE-only increment (no L2 invalidate) ----
    __shared__ unsigned sLast;
    if (tid == 0) {
        unsigned prev = __hip_atomic_fetch_add(counter, 1u, __ATOMIC_RELEASE,
                                               __HIP_MEMORY_SCOPE_AGENT);
        sLast = (prev == NBLK - 1) ? 1u : 0u;
    }
    __syncthreads();
    if (sLast) {
        float s1 = 0.f, s2 = 0.f;
        for (int i = tid; i < NBLK; i += 256) {
            s1 += __hip_atomic_load(&partials[2 * i],     __ATOMIC_RELAXED, __HIP_MEMORY_SCOPE_AGENT);
            s2 += __hip_atomic_load(&partials[2 * i + 1], __ATOMIC_RELAXED, __HIP_MEMORY_SCOPE_AGENT);
        }
#pragma unroll
        for (int off = 32; off; off >>= 1) {
            s1 += __shfl_down(s1, off, 64);
            s2 += __shfl_down(s2, off, 64);
        }
        __shared__ float red2[8];
        if (lane == 0) { red2[wave] = s1; red2[4 + wave] = s2; }
        __syncthreads();
        if (tid == 0) {
            out[0] = (red2[0] + red2[1] + red2[2] + red2[3]) * (1.0f / NPIX);
            out[1] = (red2[4] + red2[5] + red2[6] + red2[7]) * (1.0f / NPIX);
        }
    }
}

extern "C" void kernel_launch(void* const* d_in, const int* in_sizes, int n_in,
                              void* d_out, int out_size, void* d_ws, size_t ws_size,
                              hipStream_t stream) {
    (void)in_sizes; (void)n_in; (void)out_size; (void)ws_size;
    const float* former  = (const float*)d_in[0];
    const float* latter  = (const float*)d_in[1];
    const float* flow1   = (const float*)d_in[2];
    const float* flow2   = (const float*)d_in[3];
    const float* fw_mask = (const float*)d_in[4];
    const float* bw_mask = (const float*)d_in[5];
    float* out = (float*)d_out;
    float* ws  = (float*)d_ws;
    float* gf       = ws;                         // NPIX floats
    float* gl       = ws + NPIX;                  // NPIX floats
    float* partials = ws + 2 * (size_t)NPIX;      // 2*NBLK floats
    unsigned* counter = (unsigned*)(ws + 2 * (size_t)NPIX + 2 * NBLK);

    gray_kernel<<<(NP4 + 255) / 256, 256, 0, stream>>>(former, latter, gf, gl, counter);
    fused_kernel<<<dim3(NBX, NBY, BB), 256, 0, stream>>>(gf, gl, flow1, flow2,
                                                         fw_mask, bw_mask,
                                                         partials, counter, out);
}

// Round 8
// 169.978 us; speedup vs baseline: 2.1045x; 1.1559x over previous
//
#include <hip/hip_runtime.h>

#define BB 4
#define H 320
#define W 768
#define P (H*W)           // 245760
#define NPIX (BB*P)       // 983040
#define P4 (P/4)          // 61440
#define NP4 (NPIX/4)      // 245760

#define TX 32
#define TY 8
#define TW (TX+6)  // 38
#define TH (TY+6)  // 14
#define HALO (TW*TH)      // 532
#define NBX (W/TX)        // 24
#define NBY (H/TY)        // 40
#define NBLK (NBX*NBY*BB) // 3840

typedef float f4 __attribute__((ext_vector_type(4)));

// ---------------- gray kernel (float4-vectorized) ----------------
// Also resets the last-block counter (stream order puts it before fused).
__global__ __launch_bounds__(256)
void gray_kernel(const float* __restrict__ former,
                 const float* __restrict__ latter,
                 float* __restrict__ gf, float* __restrict__ gl,
                 unsigned* __restrict__ counter) {
    int idx = blockIdx.x * blockDim.x + threadIdx.x;
    if (idx == 0) *counter = 0u;
    if (idx >= NP4) return;
    int b = idx / P4;
    int r4 = idx - b * P4;
    const float* fb = former + (size_t)b * 3 * P;
    const float* lb = latter + (size_t)b * 3 * P;
    const f4 fr = *((const f4*)fb + r4);
    const f4 fg = *((const f4*)(fb + P) + r4);
    const f4 fbl = *((const f4*)(fb + 2 * P) + r4);
    const f4 lr = *((const f4*)lb + r4);
    const f4 lg = *((const f4*)(lb + P) + r4);
    const f4 lbl = *((const f4*)(lb + 2 * P) + r4);
    f4 go, lo;
#pragma unroll
    for (int k = 0; k < 4; ++k) {
        go[k] = (0.299f * fr[k] + 0.587f * fg[k] + 0.114f * fbl[k]) * 255.f;
        lo[k] = (0.299f * lr[k] + 0.587f * lg[k] + 0.114f * lbl[k]) * 255.f;
    }
    *((f4*)gf + (size_t)b * P4 + r4) = go;
    *((f4*)gl + (size_t)b * P4 + r4) = lo;
}

__device__ __forceinline__ float bilinear(const float* __restrict__ img, float fx, float fy) {
    float x0 = floorf(fx), y0 = floorf(fy);
    float wx = fx - x0, wy = fy - y0;
    float x0c = fminf(fmaxf(x0,       0.f), (float)(W - 1));
    float x1c = fminf(fmaxf(x0 + 1.f, 0.f), (float)(W - 1));
    float y0c = fminf(fmaxf(y0,       0.f), (float)(H - 1));
    float y1c = fminf(fmaxf(y0 + 1.f, 0.f), (float)(H - 1));
    int x0i = (int)x0c, x1i = (int)x1c, y0i = (int)y0c, y1i = (int)y1c;
    float Ia = img[y0i * W + x0i], Ib = img[y0i * W + x1i];
    float Ic = img[y1i * W + x0i], Id = img[y1i * W + x1i];
    float omx = 1.f - wx, omy = 1.f - wy;
    return Ia * omx * omy + Ib * wx * omy + Ic * omx * wy + Id * wx * wy;
}

// ---------------- fused warp + census + distance + charbonnier + reduce ------
// Tail discipline v3: ZERO cache-maintenance ops.
//   R6 lesson: ACQ_REL + threadfence -> per-block L2 invalidate storm (235us).
//   R7 lesson: RELEASE -> per-block buffer_wbl2 L2 tag-walks still cost ~75us.
//   Now: partials stored via RELAXED agent-scope atomic stores (sc1 -> LLC,
//   the agent coherence point), ordered before the RELAXED counter bump by a
//   raw `s_waitcnt vmcnt(0)` (HW guarantee: stores reached LLC). Last block
//   reads partials via relaxed agent atomic loads (sc1, from LLC). No wbl2,
//   no inv, nothing touches the XCD L2 pipelines.
__global__ __launch_bounds__(256, 8)
void fused_kernel(const float* __restrict__ gf, const float* __restrict__ gl,
                  const float* __restrict__ flow1, const float* __restrict__ flow2,
                  const float* __restrict__ fw_mask, const float* __restrict__ bw_mask,
                  float* __restrict__ partials, unsigned* __restrict__ counter,
                  float* __restrict__ out) {
    __shared__ f4 sT[HALO];
    const int b   = blockIdx.z;
    const int tx0 = blockIdx.x * TX;
    const int ty0 = blockIdx.y * TY;
    const int tid = threadIdx.x;

    const float* pGF = gf + (size_t)b * P;
    const float* pGL = gl + (size_t)b * P;
    const float* pU1 = flow1 + (size_t)b * 2 * P;
    const float* pU2 = flow2 + (size_t)b * 2 * P;

    for (int i = tid; i < HALO; i += 256) {
        int ly = i / TW, lx = i - ly * TW;
        int gx = min(max(tx0 - 3 + lx, 0), W - 1);
        int gy = min(max(ty0 - 3 + ly, 0), H - 1);
        int o = gy * W + gx;
        float A = pGF[o];
        float C = pGL[o];
        float u1 = pU1[o], v1 = pU1[P + o];
        float u2 = pU2[o], v2 = pU2[P + o];
        float Bv = bilinear(pGL, (float)gx + u1, (float)gy + v1);
        float D  = bilinear(pGF, (float)gx + u2, (float)gy + v2);
        sT[i] = (f4){A, Bv, C, D};
    }
    __syncthreads();

    const int lx = tid & 31, ly = tid >> 5;
    const int x = tx0 + lx, y = ty0 + ly;
    float sum1 = 0.f, sum2 = 0.f;

    if (x >= 3 && x < W - 3 && y >= 3 && y < H - 3) {
        const float m1 = fw_mask[(size_t)b * P + y * W + x];
        const float m2 = bw_mask[(size_t)b * P + y * W + x];
        const int c = (ly + 3) * TW + (lx + 3);
        const f4 cv = sT[c];
        const float c1 = cv.x, c2 = cv.y, c3 = cv.z, c4 = cv.w;
        float acc1a = 0.f, acc1b = 0.f, acc2a = 0.f, acc2b = 0.f;
#pragma unroll
        for (int dy = 0; dy < 7; ++dy) {
            const int ro = (ly + dy) * TW + lx;
#pragma unroll
            for (int dx = 0; dx < 7; ++dx) {
                if (dy == 3 && dx == 3) continue;    // center tap == 0 exactly
                const f4 n = sT[ro + dx];            // one ds_read_b128
                // loss 1: (t1-t2)^2 via ONE rsq:  s = rsq(qa*qb)
                const float a1 = n.x - c1, b1 = n.y - c2;
                const float qa1 = fmaf(a1, a1, 0.81f), qb1 = fmaf(b1, b1, 0.81f);
                const float pr1 = qa1 * qb1;
                const float s1 = __builtin_amdgcn_rsqf(pr1);
                const float num1 = fmaf(-0.81f, qa1 + qb1, pr1 + pr1);
                const float d1 = fmaf(num1, s1 * s1, ((a1 * b1) * s1) * -2.f);
                // loss 2
                const float a2 = n.z - c3, b2 = n.w - c4;
                const float qa2 = fmaf(a2, a2, 0.81f), qb2 = fmaf(b2, b2, 0.81f);
                const float pr2 = qa2 * qb2;
                const float s2 = __builtin_amdgcn_rsqf(pr2);
                const float num2 = fmaf(-0.81f, qa2 + qb2, pr2 + pr2);
                const float d2 = fmaf(num2, s2 * s2, ((a2 * b2) * s2) * -2.f);
                // shared rcp across the two losses
                const float e1 = d1 + 0.1f, e2 = d2 + 0.1f;
                const float ir = __builtin_amdgcn_rcpf(e1 * e2);
                const float g1 = (d1 * e2) * ir;
                const float g2 = (d2 * e1) * ir;
                if (dx & 1) { acc1a += g1; acc2a += g2; }
                else        { acc1b += g1; acc2b += g2; }
            }
        }
        const float dist1 = acc1a + acc1b;
        const float dist2 = acc2a + acc2b;
        sum1 = exp2f(0.45f * log2f(fmaf(dist1, dist1, 1e-6f))) * m1;
        sum2 = exp2f(0.45f * log2f(fmaf(dist2, dist2, 1e-6f))) * m2;
    }

#pragma unroll
    for (int off = 32; off; off >>= 1) {
        sum1 += __shfl_down(sum1, off, 64);
        sum2 += __shfl_down(sum2, off, 64);
    }
    __shared__ float red[8];
    const int wave = tid >> 6, lane = tid & 63;
    if (lane == 0) { red[wave] = sum1; red[4 + wave] = sum2; }
    __syncthreads();

    __shared__ unsigned sLast;
    if (tid == 0) {
        const int blk = (blockIdx.z * NBY + blockIdx.y) * NBX + blockIdx.x;
        // partials -> LLC via relaxed agent-scope atomic stores (no fences)
        __hip_atomic_store(&partials[2 * blk],     red[0] + red[1] + red[2] + red[3],
                           __ATOMIC_RELAXED, __HIP_MEMORY_SCOPE_AGENT);
        __hip_atomic_store(&partials[2 * blk + 1], red[4] + red[5] + red[6] + red[7],
                           __ATOMIC_RELAXED, __HIP_MEMORY_SCOPE_AGENT);
        // HW ordering: stores acked at LLC before the counter bump issues.
        asm volatile("s_waitcnt vmcnt(0)" ::: "memory");
        unsigned prev = __hip_atomic_fetch_add(counter, 1u, __ATOMIC_RELAXED,
                                               __HIP_MEMORY_SCOPE_AGENT);
        sLast = (prev == NBLK - 1) ? 1u : 0u;
    }
    __syncthreads();
    if (sLast) {
        float s1 = 0.f, s2 = 0.f;
        for (int i = tid; i < NBLK; i += 256) {
            s1 += __hip_atomic_load(&partials[2 * i],     __ATOMIC_RELAXED, __HIP_MEMORY_SCOPE_AGENT);
            s2 += __hip_atomic_load(&partials[2 * i + 1], __ATOMIC_RELAXED, __HIP_MEMORY_SCOPE_AGENT);
        }
#pragma unroll
        for (int off = 32; off; off >>= 1) {
            s1 += __shfl_down(s1, off, 64);
            s2 += __shfl_down(s2, off, 64);
        }
        __shared__ float red2[8];
        if (lane == 0) { red2[wave] = s1; red2[4 + wave] = s2; }
        __syncthreads();
        if (tid == 0) {
            out[0] = (red2[0] + red2[1] + red2[2] + red2[3]) * (1.0f / NPIX);
            out[1] = (red2[4] + red2[5] + red2[6] + red2[7]) * (1.0f / NPIX);
        }
    }
}

extern "C" void kernel_launch(void* const* d_in, const int* in_sizes, int n_in,
                              void* d_out, int out_size, void* d_ws, size_t ws_size,
                              hipStream_t stream) {
    (void)in_sizes; (void)n_in; (void)out_size; (void)ws_size;
    const float* former  = (const float*)d_in[0];
    const float* latter  = (const float*)d_in[1];
    const float* flow1   = (const float*)d_in[2];
    const float* flow2   = (const float*)d_in[3];
    const float* fw_mask = (const float*)d_in[4];
    const float* bw_mask = (const float*)d_in[5];
    float* out = (float*)d_out;
    float* ws  = (float*)d_ws;
    float* gf       = ws;                         // NPIX floats
    float* gl       = ws + NPIX;                  // NPIX floats
    float* partials = ws + 2 * (size_t)NPIX;      // 2*NBLK floats
    unsigned* counter = (unsigned*)(ws + 2 * (size_t)NPIX + 2 * NBLK);

    gray_kernel<<<(NP4 + 255) / 256, 256, 0, stream>>>(former, latter, gf, gl, counter);
    fused_kernel<<<dim3(NBX, NBY, BB), 256, 0, stream>>>(gf, gl, flow1, flow2,
                                                         fw_mask, bw_mask,
                                                         partials, counter, out);
}

// Round 9
// 144.096 us; speedup vs baseline: 2.4825x; 1.1796x over previous
//
#include <hip/hip_runtime.h>

#define BB 4
#define H 320
#define W 768
#define P (H*W)           // 245760
#define NPIX (BB*P)       // 983040
#define P4 (P/4)          // 61440
#define NP4 (NPIX/4)      // 245760

#define TX 32
#define TY 8
#define TW (TX+6)  // 38
#define TH (TY+6)  // 14
#define HALO (TW*TH)      // 532
#define NBX (W/TX)        // 24
#define NBY (H/TY)        // 40
#define NBLK (NBX*NBY*BB) // 3840

typedef float f4 __attribute__((ext_vector_type(4)));

// ---------------- gray kernel (float4-vectorized) ----------------
// Also resets the last-block counter (stream order puts it before fused).
__global__ __launch_bounds__(256)
void gray_kernel(const float* __restrict__ former,
                 const float* __restrict__ latter,
                 float* __restrict__ gf, float* __restrict__ gl,
                 unsigned* __restrict__ counter) {
    int idx = blockIdx.x * blockDim.x + threadIdx.x;
    if (idx == 0) *counter = 0u;
    if (idx >= NP4) return;
    int b = idx / P4;
    int r4 = idx - b * P4;
    const float* fb = former + (size_t)b * 3 * P;
    const float* lb = latter + (size_t)b * 3 * P;
    const f4 fr = *((const f4*)fb + r4);
    const f4 fg = *((const f4*)(fb + P) + r4);
    const f4 fbl = *((const f4*)(fb + 2 * P) + r4);
    const f4 lr = *((const f4*)lb + r4);
    const f4 lg = *((const f4*)(lb + P) + r4);
    const f4 lbl = *((const f4*)(lb + 2 * P) + r4);
    f4 go, lo;
#pragma unroll
    for (int k = 0; k < 4; ++k) {
        go[k] = (0.299f * fr[k] + 0.587f * fg[k] + 0.114f * fbl[k]) * 255.f;
        lo[k] = (0.299f * lr[k] + 0.587f * lg[k] + 0.114f * lbl[k]) * 255.f;
    }
    *((f4*)gf + (size_t)b * P4 + r4) = go;
    *((f4*)gl + (size_t)b * P4 + r4) = lo;
}

__device__ __forceinline__ float bilinear(const float* __restrict__ img, float fx, float fy) {
    float x0 = floorf(fx), y0 = floorf(fy);
    float wx = fx - x0, wy = fy - y0;
    float x0c = fminf(fmaxf(x0,       0.f), (float)(W - 1));
    float x1c = fminf(fmaxf(x0 + 1.f, 0.f), (float)(W - 1));
    float y0c = fminf(fmaxf(y0,       0.f), (float)(H - 1));
    float y1c = fminf(fmaxf(y0 + 1.f, 0.f), (float)(H - 1));
    int x0i = (int)x0c, x1i = (int)x1c, y0i = (int)y0c, y1i = (int)y1c;
    float Ia = img[y0i * W + x0i], Ib = img[y0i * W + x1i];
    float Ic = img[y1i * W + x0i], Id = img[y1i * W + x1i];
    float omx = 1.f - wx, omy = 1.f - wy;
    return Ia * omx * omy + Ib * wx * omy + Ic * omx * wy + Id * wx * wy;
}

// ---------------- fused warp + census + distance + charbonnier + reduce ------
// Tail discipline v3 (validated R8): ZERO cache-maintenance ops.
//   R6 lesson: ACQ_REL + threadfence -> per-block L2 invalidate storm (235us).
//   R7 lesson: RELEASE -> per-block buffer_wbl2 L2 tag-walks cost ~75us.
//   Now: partials via RELAXED agent-scope atomic stores (sc1 -> LLC, the
//   agent coherence point), ordered before the RELAXED counter bump by a raw
//   `s_waitcnt vmcnt(0)`. Last block reads partials via relaxed agent atomic
//   loads. No wbl2, no inv.
// R8 lesson: __launch_bounds__(256,8) capped VGPR->32 and spilled ~187 MB to
// scratch (WRITE_SIZE 105 MB), making the kernel spill-BW-bound. Keep (256,5)
// (44-48 VGPR, zero spill).
__global__ __launch_bounds__(256, 5)
void fused_kernel(const float* __restrict__ gf, const float* __restrict__ gl,
                  const float* __restrict__ flow1, const float* __restrict__ flow2,
                  const float* __restrict__ fw_mask, const float* __restrict__ bw_mask,
                  float* __restrict__ partials, unsigned* __restrict__ counter,
                  float* __restrict__ out) {
    __shared__ f4 sT[HALO];
    const int b   = blockIdx.z;
    const int tx0 = blockIdx.x * TX;
    const int ty0 = blockIdx.y * TY;
    const int tid = threadIdx.x;

    const float* pGF = gf + (size_t)b * P;
    const float* pGL = gl + (size_t)b * P;
    const float* pU1 = flow1 + (size_t)b * 2 * P;
    const float* pU2 = flow2 + (size_t)b * 2 * P;

    for (int i = tid; i < HALO; i += 256) {
        int ly = i / TW, lx = i - ly * TW;
        int gx = min(max(tx0 - 3 + lx, 0), W - 1);
        int gy = min(max(ty0 - 3 + ly, 0), H - 1);
        int o = gy * W + gx;
        float A = pGF[o];
        float C = pGL[o];
        float u1 = pU1[o], v1 = pU1[P + o];
        float u2 = pU2[o], v2 = pU2[P + o];
        float Bv = bilinear(pGL, (float)gx + u1, (float)gy + v1);
        float D  = bilinear(pGF, (float)gx + u2, (float)gy + v2);
        sT[i] = (f4){A, Bv, C, D};
    }
    __syncthreads();

    const int lx = tid & 31, ly = tid >> 5;
    const int x = tx0 + lx, y = ty0 + ly;
    float sum1 = 0.f, sum2 = 0.f;

    if (x >= 3 && x < W - 3 && y >= 3 && y < H - 3) {
        const float m1 = fw_mask[(size_t)b * P + y * W + x];
        const float m2 = bw_mask[(size_t)b * P + y * W + x];
        const int c = (ly + 3) * TW + (lx + 3);
        const f4 cv = sT[c];
        const float c1 = cv.x, c2 = cv.y, c3 = cv.z, c4 = cv.w;
        float acc1a = 0.f, acc1b = 0.f, acc2a = 0.f, acc2b = 0.f;
#pragma unroll
        for (int dy = 0; dy < 7; ++dy) {
            const int ro = (ly + dy) * TW + lx;
#pragma unroll
            for (int dx = 0; dx < 7; ++dx) {
                if (dy == 3 && dx == 3) continue;    // center tap == 0 exactly
                const f4 n = sT[ro + dx];            // one ds_read_b128
                // loss 1: (t1-t2)^2 via ONE rsq:  s = rsq(qa*qb)
                const float a1 = n.x - c1, b1 = n.y - c2;
                const float qa1 = fmaf(a1, a1, 0.81f), qb1 = fmaf(b1, b1, 0.81f);
                const float pr1 = qa1 * qb1;
                const float s1 = __builtin_amdgcn_rsqf(pr1);
                const float num1 = fmaf(-0.81f, qa1 + qb1, pr1 + pr1);
                const float d1 = fmaf(num1, s1 * s1, ((a1 * b1) * s1) * -2.f);
                // loss 2
                const float a2 = n.z - c3, b2 = n.w - c4;
                const float qa2 = fmaf(a2, a2, 0.81f), qb2 = fmaf(b2, b2, 0.81f);
                const float pr2 = qa2 * qb2;
                const float s2 = __builtin_amdgcn_rsqf(pr2);
                const float num2 = fmaf(-0.81f, qa2 + qb2, pr2 + pr2);
                const float d2 = fmaf(num2, s2 * s2, ((a2 * b2) * s2) * -2.f);
                // shared rcp across the two losses
                const float e1 = d1 + 0.1f, e2 = d2 + 0.1f;
                const float ir = __builtin_amdgcn_rcpf(e1 * e2);
                const float g1 = (d1 * e2) * ir;
                const float g2 = (d2 * e1) * ir;
                if (dx & 1) { acc1a += g1; acc2a += g2; }
                else        { acc1b += g1; acc2b += g2; }
            }
        }
        const float dist1 = acc1a + acc1b;
        const float dist2 = acc2a + acc2b;
        sum1 = exp2f(0.45f * log2f(fmaf(dist1, dist1, 1e-6f))) * m1;
        sum2 = exp2f(0.45f * log2f(fmaf(dist2, dist2, 1e-6f))) * m2;
    }

#pragma unroll
    for (int off = 32; off; off >>= 1) {
        sum1 += __shfl_down(sum1, off, 64);
        sum2 += __shfl_down(sum2, off, 64);
    }
    __shared__ float red[8];
    const int wave = tid >> 6, lane = tid & 63;
    if (lane == 0) { red[wave] = sum1; red[4 + wave] = sum2; }
    __syncthreads();

    __shared__ unsigned sLast;
    if (tid == 0) {
        const int blk = (blockIdx.z * NBY + blockIdx.y) * NBX + blockIdx.x;
        // partials -> LLC via relaxed agent-scope atomic stores (no fences)
        __hip_atomic_store(&partials[2 * blk],     red[0] + red[1] + red[2] + red[3],
                           __ATOMIC_RELAXED, __HIP_MEMORY_SCOPE_AGENT);
        __hip_atomic_store(&partials[2 * blk + 1], red[4] + red[5] + red[6] + red[7],
                           __ATOMIC_RELAXED, __HIP_MEMORY_SCOPE_AGENT);
        // HW ordering: stores acked at LLC before the counter bump issues.
        asm volatile("s_waitcnt vmcnt(0)" ::: "memory");
        unsigned prev = __hip_atomic_fetch_add(counter, 1u, __ATOMIC_RELAXED,
                                               __HIP_MEMORY_SCOPE_AGENT);
        sLast = (prev == NBLK - 1) ? 1u : 0u;
    }
    __syncthreads();
    if (sLast) {
        float s1 = 0.f, s2 = 0.f;
        for (int i = tid; i < NBLK; i += 256) {
            s1 += __hip_atomic_load(&partials[2 * i],     __ATOMIC_RELAXED, __HIP_MEMORY_SCOPE_AGENT);
            s2 += __hip_atomic_load(&partials[2 * i + 1], __ATOMIC_RELAXED, __HIP_MEMORY_SCOPE_AGENT);
        }
#pragma unroll
        for (int off = 32; off; off >>= 1) {
            s1 += __shfl_down(s1, off, 64);
            s2 += __shfl_down(s2, off, 64);
        }
        __shared__ float red2[8];
        if (lane == 0) { red2[wave] = s1; red2[4 + wave] = s2; }
        __syncthreads();
        if (tid == 0) {
            out[0] = (red2[0] + red2[1] + red2[2] + red2[3]) * (1.0f / NPIX);
            out[1] = (red2[4] + red2[5] + red2[6] + red2[7]) * (1.0f / NPIX);
        }
    }
}

extern "C" void kernel_launch(void* const* d_in, const int* in_sizes, int n_in,
                              void* d_out, int out_size, void* d_ws, size_t ws_size,
                              hipStream_t stream) {
    (void)in_sizes; (void)n_in; (void)out_size; (void)ws_size;
    const float* former  = (const float*)d_in[0];
    const float* latter  = (const float*)d_in[1];
    const float* flow1   = (const float*)d_in[2];
    const float* flow2   = (const float*)d_in[3];
    const float* fw_mask = (const float*)d_in[4];
    const float* bw_mask = (const float*)d_in[5];
    float* out = (float*)d_out;
    float* ws  = (float*)d_ws;
    float* gf       = ws;                         // NPIX floats
    float* gl       = ws + NPIX;                  // NPIX floats
    float* partials = ws + 2 * (size_t)NPIX;      // 2*NBLK floats
    unsigned* counter = (unsigned*)(ws + 2 * (size_t)NPIX + 2 * NBLK);

    gray_kernel<<<(NP4 + 255) / 256, 256, 0, stream>>>(former, latter, gf, gl, counter);
    fused_kernel<<<dim3(NBX, NBY, BB), 256, 0, stream>>>(gf, gl, flow1, flow2,
                                                         fw_mask, bw_mask,
                                                         partials, counter, out);
}